// Round 4
// baseline (3738.349 us; speedup 1.0000x reference)
//
#include <hip/hip_runtime.h>
#include <math.h>
#include <stdint.h>

#define HD    128      // hidden
#define GATES 512      // 4H
#define BB    64       // batch
#define CL    512      // context len
#define QL    64       // query len

#define TM 128
#define TN 128
#define TK 32

typedef __attribute__((ext_vector_type(8))) short short8_t;
typedef __attribute__((ext_vector_type(4))) short short4_t;
typedef __attribute__((ext_vector_type(4))) float f32x4;

__device__ __forceinline__ float fast_sigmoid(float x) {
    float e = __builtin_amdgcn_exp2f(-1.44269504f * x);
    return __builtin_amdgcn_rcpf(1.f + e);
}
__device__ __forceinline__ float fast_tanh(float x) {
    float e = __builtin_amdgcn_exp2f(2.88539008f * x);
    float r = __builtin_amdgcn_rcpf(e + 1.f);
    return 1.f - 2.f * r;
}
__device__ __forceinline__ float lane_bcast(float v, int k) {
    return __uint_as_float(__builtin_amdgcn_readlane(__float_as_uint(v), k));
}

// ---------------------------------------------------------------------------
// Split W (2*512, K) fp32 into 3 bf16 planes, each (2*512, Ksp), zero-padded.
// ---------------------------------------------------------------------------
__global__ __launch_bounds__(256)
void splitW_k(const float* __restrict__ W, ushort* __restrict__ P, int K, int Ksp)
{
    int idx = blockIdx.x * 256 + threadIdx.x;
    int per_row = Ksp >> 2;
    int total = 1024 * per_row;
    if (idx >= total) return;
    int row = idx / per_row;
    int c4  = (idx - row * per_row) * 4;

    short4_t o1, o2, o3;
#pragma unroll
    for (int e = 0; e < 4; ++e) {
        int k = c4 + e;
        float x = (k < K) ? W[(size_t)row * K + k] : 0.f;
        uint32_t u1 = __float_as_uint(x) & 0xffff0000u;
        float r1 = x - __uint_as_float(u1);
        uint32_t u2 = __float_as_uint(r1) & 0xffff0000u;
        float r2 = r1 - __uint_as_float(u2);
        uint32_t u3 = __float_as_uint(r2) & 0xffff0000u;
        o1[e] = (short)(u1 >> 16);
        o2[e] = (short)(u2 >> 16);
        o3[e] = (short)(u3 >> 16);
    }
    size_t base = (size_t)row * Ksp + c4;
    size_t ps = (size_t)1024 * Ksp;
    *reinterpret_cast<short4_t*>(&P[base]) = o1;
    *reinterpret_cast<short4_t*>(&P[ps + base]) = o2;
    *reinterpret_cast<short4_t*>(&P[2 * ps + base]) = o3;
}

// ---------------------------------------------------------------------------
// MFMA GEMM, bf16x3 split (6 cross-term MFMAs per k-tile).
// ---------------------------------------------------------------------------
__global__ __launch_bounds__(256)
void gemm_bf16x3(const float* __restrict__ A, const int* __restrict__ gidx,
                 const ushort* __restrict__ Wpl, const float* __restrict__ bias,
                 float* __restrict__ C, int M, int K, int Ksp)
{
    const int dir  = blockIdx.z;
    const int m0   = blockIdx.x * TM;
    const int n0   = blockIdx.y * TN;
    const int tid  = threadIdx.x;
    const int lane = tid & 63;
    const int wid  = tid >> 6;
    const int wm   = (wid >> 1) * 64;
    const int wn   = (wid & 1) * 64;

    __shared__ __align__(16) ushort As[3][TM * TK];
    __shared__ __align__(16) ushort Bs[3][TN * TK];

    const int ar = tid >> 3;
    const int ac = (tid & 7) * 4;

    size_t arow[4];
#pragma unroll
    for (int r = 0; r < 4; ++r) {
        int m = m0 + ar + r * 32;
        arow[r] = gidx ? (size_t)gidx[m] : (size_t)m;
    }

    f32x4 acc[4][4];
#pragma unroll
    for (int i = 0; i < 4; ++i)
#pragma unroll
        for (int j = 0; j < 4; ++j) acc[i][j] = (f32x4)0.f;

    const size_t wps    = (size_t)1024 * Ksp;
    const size_t wdbase = (size_t)dir * 512 * Ksp;

    for (int k0 = 0; k0 < Ksp; k0 += TK) {
#pragma unroll
        for (int r = 0; r < 4; ++r) {
            float4 v = make_float4(0.f, 0.f, 0.f, 0.f);
            if (k0 + ac < K) v = *(const float4*)(A + arow[r] * K + k0 + ac);
            float xs[4] = {v.x, v.y, v.z, v.w};
            short4_t o1, o2, o3;
#pragma unroll
            for (int e = 0; e < 4; ++e) {
                uint32_t u1 = __float_as_uint(xs[e]) & 0xffff0000u;
                float r1 = xs[e] - __uint_as_float(u1);
                uint32_t u2 = __float_as_uint(r1) & 0xffff0000u;
                float r2 = r1 - __uint_as_float(u2);
                uint32_t u3 = __float_as_uint(r2) & 0xffff0000u;
                o1[e] = (short)(u1 >> 16);
                o2[e] = (short)(u2 >> 16);
                o3[e] = (short)(u3 >> 16);
            }
            int wb = (ar + r * 32) * TK + ac;
            *reinterpret_cast<short4_t*>(&As[0][wb]) = o1;
            *reinterpret_cast<short4_t*>(&As[1][wb]) = o2;
            *reinterpret_cast<short4_t*>(&As[2][wb]) = o3;
        }
#pragma unroll
        for (int t = 0; t < 6; ++t) {
            int chunk = wid * 6 + t;
            int pl = chunk >> 3;
            int ch = chunk & 7;
            int rrow = ch * 16 + (lane >> 2);
            const ushort* src = Wpl + (size_t)pl * wps + wdbase +
                                (size_t)(n0 + rrow) * Ksp + k0 + (lane & 3) * 8;
            ushort* dst = &Bs[pl][ch * 512];
            __builtin_amdgcn_global_load_lds(
                reinterpret_cast<const __attribute__((address_space(1))) void*>(
                    reinterpret_cast<uintptr_t>(src)),
                reinterpret_cast<__attribute__((address_space(3))) void*>(
                    reinterpret_cast<uintptr_t>(dst)),
                16, 0, 0);
        }
        __syncthreads();

        const int koff = (lane >> 4) * 8;
        short8_t bf0[4], bf1[4], bf2[4];
#pragma unroll
        for (int j = 0; j < 4; ++j) {
            int nrow = wn + j * 16 + (lane & 15);
            bf0[j] = *reinterpret_cast<const short8_t*>(&Bs[0][nrow * TK + koff]);
            bf1[j] = *reinterpret_cast<const short8_t*>(&Bs[1][nrow * TK + koff]);
            bf2[j] = *reinterpret_cast<const short8_t*>(&Bs[2][nrow * TK + koff]);
        }
#pragma unroll
        for (int i = 0; i < 4; ++i) {
            int mrow = wm + i * 16 + (lane & 15);
            short8_t a1 = *reinterpret_cast<const short8_t*>(&As[0][mrow * TK + koff]);
            short8_t a2 = *reinterpret_cast<const short8_t*>(&As[1][mrow * TK + koff]);
            short8_t a3 = *reinterpret_cast<const short8_t*>(&As[2][mrow * TK + koff]);
#pragma unroll
            for (int j = 0; j < 4; ++j) {
                f32x4 c = acc[i][j];
                c = __builtin_amdgcn_mfma_f32_16x16x32_bf16(a1, bf0[j], c, 0, 0, 0);
                c = __builtin_amdgcn_mfma_f32_16x16x32_bf16(a1, bf1[j], c, 0, 0, 0);
                c = __builtin_amdgcn_mfma_f32_16x16x32_bf16(a2, bf0[j], c, 0, 0, 0);
                c = __builtin_amdgcn_mfma_f32_16x16x32_bf16(a2, bf1[j], c, 0, 0, 0);
                c = __builtin_amdgcn_mfma_f32_16x16x32_bf16(a1, bf2[j], c, 0, 0, 0);
                c = __builtin_amdgcn_mfma_f32_16x16x32_bf16(a3, bf0[j], c, 0, 0, 0);
                acc[i][j] = c;
            }
        }
        __syncthreads();
    }

    float* Cd = C + (size_t)dir * M * 512;
#pragma unroll
    for (int j = 0; j < 4; ++j) {
        int col = n0 + wn + j * 16 + (lane & 15);
        float bv = bias[dir * 512 + col];
#pragma unroll
        for (int i = 0; i < 4; ++i) {
            int rbase = m0 + wm + i * 16 + ((lane >> 4) << 2);
#pragma unroll
            for (int r = 0; r < 4; ++r)
                Cd[(size_t)(rbase + r) * 512 + col] = acc[i][j][r] + bv;
        }
    }
}

// ---------------------------------------------------------------------------
// LSTM scan v3: block per (batch, dir[, layer via z]); 512 threads.
// Thread (p = wave>>1, h_idx = tid&127) computes partials for ALL 4 gates of
// hidden unit h_idx over k-slice [32p, 32p+32), using 1 ds_read + 32
// v_readlane broadcasts (each feeding 4 FMAs). Partials summed by tid<128
// update threads. No LDS broadcast storm (was 256 b128/step).
// ---------------------------------------------------------------------------
__global__ __launch_bounds__(512)
void lstm_scan3(const float* __restrict__ xgP, const float* __restrict__ WhhP,
                float* __restrict__ hoP, int TP,
                const float* __restrict__ xgQ, const float* __restrict__ WhhQ,
                float* __restrict__ hoQ, int TQ)
{
    const int b    = blockIdx.x;
    const int dir  = blockIdx.y;
    const int tid  = threadIdx.x;
    const int lane = tid & 63;
    const int p    = tid >> 7;          // k-slice 0..3 (wave-uniform: wave>>1)
    const int hidx = tid & 127;
    const int kb   = p * 32;

    const float* xg; const float* Whh; float* ho; int T;
    if (blockIdx.z == 0) { xg = xgP; Whh = WhhP; ho = hoP; T = TP; }
    else                 { xg = xgQ; Whh = WhhQ; ho = hoQ; T = TQ; }

    const float* xgd = xg + (size_t)dir * BB * T * GATES;

    // weights: w[g][kk] = Whh[(dir*512 + g*128 + hidx)*128 + kb + kk]
    float4 w[4][8];
#pragma unroll
    for (int g = 0; g < 4; ++g) {
        const float* wr = Whh + ((size_t)dir * GATES + g * 128 + hidx) * HD + kb;
#pragma unroll
        for (int u = 0; u < 8; ++u) w[g][u] = *(const float4*)(wr + u * 4);
    }

    __shared__ __align__(16) float hs[HD];
    __shared__ float part[16 * HD];     // [(p*4+g)*128 + hidx]

    if (tid < HD) hs[tid] = 0.f;
    float c = 0.f;
    __syncthreads();

    int t = dir ? (T - 1) : 0;
    const int dt = dir ? -1 : 1;

    float xcur = xgd[((size_t)b * T + t) * GATES + tid];

    for (int step = 0; step < T; ++step) {
        int tn = t + dt;
        float xnext = (step + 1 < T) ? xgd[((size_t)b * T + tn) * GATES + tid] : 0.f;

        float a0 = (p == 0) ? xcur : 0.f;
        float a1 = (p == 1) ? xcur : 0.f;
        float a2 = (p == 2) ? xcur : 0.f;
        float a3 = (p == 3) ? xcur : 0.f;

        float vh = hs[kb + (lane & 31)];
#pragma unroll
        for (int u = 0; u < 8; ++u) {
#pragma unroll
            for (int e = 0; e < 4; ++e) {
                float hk = lane_bcast(vh, u * 4 + e);
                const float* we = (const float*)&w[0][0];
                a0 += ((const float*)&w[0][u])[e] * hk;
                a1 += ((const float*)&w[1][u])[e] * hk;
                a2 += ((const float*)&w[2][u])[e] * hk;
                a3 += ((const float*)&w[3][u])[e] * hk;
                (void)we;
            }
        }
        part[(p * 4 + 0) * HD + hidx] = a0;
        part[(p * 4 + 1) * HD + hidx] = a1;
        part[(p * 4 + 2) * HD + hidx] = a2;
        part[(p * 4 + 3) * HD + hidx] = a3;
        __syncthreads();

        if (tid < HD) {
            float pre0 = (part[0 * HD + tid] + part[4 * HD + tid]) +
                         (part[8 * HD + tid] + part[12 * HD + tid]);
            float pre1 = (part[1 * HD + tid] + part[5 * HD + tid]) +
                         (part[9 * HD + tid] + part[13 * HD + tid]);
            float pre2 = (part[2 * HD + tid] + part[6 * HD + tid]) +
                         (part[10 * HD + tid] + part[14 * HD + tid]);
            float pre3 = (part[3 * HD + tid] + part[7 * HD + tid]) +
                         (part[11 * HD + tid] + part[15 * HD + tid]);
            float ig = fast_sigmoid(pre0);
            float fg = fast_sigmoid(pre1);
            float gg = fast_tanh(pre2);
            float og = fast_sigmoid(pre3);
            c = fg * c + ig * gg;
            float h = og * fast_tanh(c);
            hs[tid] = h;
            ho[((size_t)b * T + t) * 256 + dir * HD + tid] = h;
        }
        __syncthreads();
        xcur = xnext;
        t = tn;
    }
}

// ---------------------------------------------------------------------------
__global__ void rowdot(const float* __restrict__ X, const float* __restrict__ w,
                       float* __restrict__ out, int N, int D)
{
    int gw   = (int)((blockIdx.x * blockDim.x + threadIdx.x) >> 6);
    int lane = threadIdx.x & 63;
    if (gw >= N) return;
    const float* xp = X + (size_t)gw * D;
    float s = 0.f;
    for (int d = lane; d < D; d += 64) s += xp[d] * w[d];
#pragma unroll
    for (int off = 32; off; off >>= 1) s += __shfl_down(s, off);
    if (lane == 0) out[gw] = s;
}

// ---------------------------------------------------------------------------
__global__ __launch_bounds__(256)
void att_s(const float* __restrict__ co, const float* __restrict__ qo,
           const float* __restrict__ cw, const float* __restrict__ qw,
           const float* __restrict__ wcq, const float* __restrict__ attb,
           float* __restrict__ s)
{
    int b  = blockIdx.x;
    int c0 = blockIdx.y * 64;
    int tid = threadIdx.x;
    int tq = tid & 15, trc = tid >> 4;
    int cbase = c0 + trc * 4, qbase = tq * 4;

    float acc[4][4];
#pragma unroll
    for (int i = 0; i < 4; ++i)
#pragma unroll
        for (int j = 0; j < 4; ++j) acc[i][j] = 0.f;

    for (int d = 0; d < 256; d += 4) {
        float4 wv = *(const float4*)&wcq[d];
        float4 cv[4], qv[4];
#pragma unroll
        for (int i = 0; i < 4; ++i) {
            float4 v = *(const float4*)&co[((size_t)b * CL + cbase + i) * 256 + d];
            cv[i].x = v.x * wv.x; cv[i].y = v.y * wv.y;
            cv[i].z = v.z * wv.z; cv[i].w = v.w * wv.w;
        }
#pragma unroll
        for (int j = 0; j < 4; ++j)
            qv[j] = *(const float4*)&qo[((size_t)b * QL + qbase + j) * 256 + d];
#pragma unroll
        for (int i = 0; i < 4; ++i)
#pragma unroll
            for (int j = 0; j < 4; ++j)
                acc[i][j] += cv[i].x * qv[j].x + cv[i].y * qv[j].y +
                             cv[i].z * qv[j].z + cv[i].w * qv[j].w;
    }
    float ab = attb[0];
#pragma unroll
    for (int i = 0; i < 4; ++i) {
        float cwv = cw[b * CL + cbase + i];
#pragma unroll
        for (int j = 0; j < 4; ++j) {
            s[((size_t)b * CL + cbase + i) * QL + qbase + j] =
                acc[i][j] + cwv + qw[b * QL + qbase + j] + ab;
        }
    }
}

// ---------------------------------------------------------------------------
__global__ void softmax_q(float* __restrict__ s, float* __restrict__ smax)
{
    int gw   = (int)((blockIdx.x * blockDim.x + threadIdx.x) >> 6);
    int lane = threadIdx.x & 63;
    float v = s[(size_t)gw * QL + lane];
    float mx = v;
#pragma unroll
    for (int off = 32; off; off >>= 1) mx = fmaxf(mx, __shfl_xor(mx, off));
    float e = expf(v - mx);
    float sm = e;
#pragma unroll
    for (int off = 32; off; off >>= 1) sm += __shfl_xor(sm, off);
    s[(size_t)gw * QL + lane] = e / sm;
    if (lane == 0) smax[gw] = mx;
}

// ---------------------------------------------------------------------------
__global__ __launch_bounds__(512)
void bw_k(const float* __restrict__ smax, float* __restrict__ bw)
{
    int b = blockIdx.x, c = threadIdx.x;
    int lane = c & 63, wid = c >> 6;
    __shared__ float red[8];
    float v = smax[b * CL + c];
    float mx = v;
#pragma unroll
    for (int off = 32; off; off >>= 1) mx = fmaxf(mx, __shfl_xor(mx, off));
    if (lane == 0) red[wid] = mx;
    __syncthreads();
    float bm = red[0];
#pragma unroll
    for (int w = 1; w < 8; ++w) bm = fmaxf(bm, red[w]);
    float e = expf(v - bm);
    float sm = e;
#pragma unroll
    for (int off = 32; off; off >>= 1) sm += __shfl_xor(sm, off);
    __syncthreads();
    if (lane == 0) red[wid] = sm;
    __syncthreads();
    float ts = 0.f;
#pragma unroll
    for (int w = 0; w < 8; ++w) ts += red[w];
    bw[b * CL + c] = e / ts;
}

// ---------------------------------------------------------------------------
__global__ __launch_bounds__(256)
void q2c_k(const float* __restrict__ bw, const float* __restrict__ co,
           float* __restrict__ q2c)
{
    int b = blockIdx.x, d = threadIdx.x;
    float acc = 0.f;
    for (int c = 0; c < CL; ++c)
        acc += bw[b * CL + c] * co[((size_t)b * CL + c) * 256 + d];
    q2c[b * 256 + d] = acc;
}

// ---------------------------------------------------------------------------
__global__ __launch_bounds__(256)
void c2q_g(const float* __restrict__ a, const float* __restrict__ qo,
           const float* __restrict__ co, const float* __restrict__ q2c,
           float* __restrict__ g)
{
    int b  = blockIdx.x;
    int c  = blockIdx.y * 64 + (threadIdx.x >> 2);
    int gq = threadIdx.x & 3;

    float4 acc[16];
#pragma unroll
    for (int jj = 0; jj < 16; ++jj) acc[jj] = make_float4(0.f, 0.f, 0.f, 0.f);

    const float* ar = a + ((size_t)b * CL + c) * QL;
    for (int q = 0; q < QL; ++q) {
        float av = ar[q];
        const float* qr = qo + ((size_t)b * QL + q) * 256;
#pragma unroll
        for (int jj = 0; jj < 16; ++jj) {
            float4 qv = *(const float4*)&qr[4 * gq + 16 * jj];
            acc[jj].x += av * qv.x; acc[jj].y += av * qv.y;
            acc[jj].z += av * qv.z; acc[jj].w += av * qv.w;
        }
    }
    size_t gbase = ((size_t)b * CL + c) * 1024;
    const float* corow = co + ((size_t)b * CL + c) * 256;
    const float* q2cr  = q2c + b * 256;
#pragma unroll
    for (int jj = 0; jj < 16; ++jj) {
        int d = 4 * gq + 16 * jj;
        float4 cv = *(const float4*)&corow[d];
        float4 qc = *(const float4*)&q2cr[d];
        float4 cq = acc[jj];
        *(float4*)&g[gbase + d] = cv;
        *(float4*)&g[gbase + 256 + d] = cq;
        float4 t;
        t.x = cv.x * cq.x; t.y = cv.y * cq.y; t.z = cv.z * cq.z; t.w = cv.w * cq.w;
        *(float4*)&g[gbase + 512 + d] = t;
        t.x = cv.x * qc.x; t.y = cv.y * qc.y; t.z = cv.z * qc.z; t.w = cv.w * qc.w;
        *(float4*)&g[gbase + 768 + d] = t;
    }
}

// ---------------------------------------------------------------------------
__global__ void logits_k(const float* __restrict__ g, const float* __restrict__ m,
                         const float* __restrict__ m2o,
                         const float* __restrict__ p1wg, const float* __restrict__ p1wm,
                         const float* __restrict__ p1b,
                         const float* __restrict__ p2wg, const float* __restrict__ p2wm,
                         const float* __restrict__ p2b,
                         float* __restrict__ lp1, float* __restrict__ lp2)
{
    int row  = (int)((blockIdx.x * blockDim.x + threadIdx.x) >> 6);
    int lane = threadIdx.x & 63;
    const float* gr = g + (size_t)row * 1024;
    float s1 = 0.f, s2 = 0.f;
    for (int d = lane; d < 1024; d += 64) {
        float gv = gr[d];
        s1 += gv * p1wg[d];
        s2 += gv * p2wg[d];
    }
    const float* mr  = m   + (size_t)row * 256;
    const float* m2r = m2o + (size_t)row * 256;
    for (int d = lane; d < 256; d += 64) {
        s1 += mr[d] * p1wm[d];
        s2 += m2r[d] * p2wm[d];
    }
#pragma unroll
    for (int off = 32; off; off >>= 1) {
        s1 += __shfl_down(s1, off);
        s2 += __shfl_down(s2, off);
    }
    if (lane == 0) {
        lp1[row] = s1 + p1b[0];
        lp2[row] = s2 + p2b[0];
    }
}

// ---------------------------------------------------------------------------
__global__ __launch_bounds__(512)
void masked_softmax(const float* __restrict__ lp1, const float* __restrict__ lp2,
                    const int* __restrict__ p, float* __restrict__ out)
{
    int b = blockIdx.x, c = threadIdx.x;
    int lane = c & 63, wid = c >> 6;
    const float* lp = blockIdx.y ? lp2 : lp1;
    float* o = out + (size_t)blockIdx.y * BB * CL;

    __shared__ float red[8];
    float v = (p[b * CL + c] != 0) ? lp[b * CL + c] : -INFINITY;
    float mx = v;
#pragma unroll
    for (int off = 32; off; off >>= 1) mx = fmaxf(mx, __shfl_xor(mx, off));
    if (lane == 0) red[wid] = mx;
    __syncthreads();
    float bm = red[0];
#pragma unroll
    for (int w = 1; w < 8; ++w) bm = fmaxf(bm, red[w]);
    float e = expf(v - bm);
    float sm = e;
#pragma unroll
    for (int off = 32; off; off >>= 1) sm += __shfl_xor(sm, off);
    __syncthreads();
    if (lane == 0) red[wid] = sm;
    __syncthreads();
    float ts = 0.f;
#pragma unroll
    for (int w = 0; w < 8; ++w) ts += red[w];
    o[b * CL + c] = e / ts;
}

// ---------------------------------------------------------------------------
extern "C" void kernel_launch(void* const* d_in, const int* in_sizes, int n_in,
                              void* d_out, int out_size, void* d_ws, size_t ws_size,
                              hipStream_t stream)
{
    const int*   p        = (const int*)d_in[0];
    const int*   q        = (const int*)d_in[1];
    const float* emb      = (const float*)d_in[2];
    const float* qenc_Wih = (const float*)d_in[3];
    const float* qenc_Whh = (const float*)d_in[4];
    const float* qenc_b   = (const float*)d_in[5];
    const float* penc_Wih = (const float*)d_in[6];
    const float* penc_Whh = (const float*)d_in[7];
    const float* penc_b   = (const float*)d_in[8];
    const float* m1_Wih   = (const float*)d_in[9];
    const float* m1_Whh   = (const float*)d_in[10];
    const float* m1_b     = (const float*)d_in[11];
    const float* m2_Wih   = (const float*)d_in[12];
    const float* m2_Whh   = (const float*)d_in[13];
    const float* m2_b     = (const float*)d_in[14];
    const float* out_Wih  = (const float*)d_in[15];
    const float* out_Whh  = (const float*)d_in[16];
    const float* out_b    = (const float*)d_in[17];
    const float* att_wc   = (const float*)d_in[18];
    const float* att_wq   = (const float*)d_in[19];
    const float* att_wcq  = (const float*)d_in[20];
    const float* att_b    = (const float*)d_in[21];
    const float* p1_wg    = (const float*)d_in[22];
    const float* p1_wm    = (const float*)d_in[23];
    const float* p1_b     = (const float*)d_in[24];
    const float* p2_wg    = (const float*)d_in[25];
    const float* p2_wm    = (const float*)d_in[26];
    const float* p2_b     = (const float*)d_in[27];

    float* ws = (float*)d_ws;
    size_t off = 0;
    auto alloc = [&](size_t n) { float* r = ws + off; off += n; return r; };
    auto allocU = [&](size_t nsh) { ushort* r = (ushort*)(ws + off); off += (nsh + 1) / 2; return r; };

    const size_t NC = (size_t)BB * CL;     // 32768
    const size_t NQ = (size_t)BB * QL;     // 4096

    float* xgA  = alloc(2 * NC * GATES);   // gate preacts, reused per layer
    float* gbuf = alloc(NC * 1024);        // g  (xgQ aliases its head: dead before g written)
    float* xgQ  = gbuf;
    float* co   = alloc(NC * 256);
    float* qo   = alloc(NQ * 256);
    float* sbuf = alloc(NC * QL);          // s, then a (in place)
    float* cw   = alloc(NC);
    float* qw   = alloc(NQ);
    float* smax = alloc(NC);
    float* bw   = alloc(NC);
    float* q2c  = alloc((size_t)BB * 256);
    float* mmid = alloc(NC * 256);
    float* mbuf = alloc(NC * 256);
    float* m2o  = alloc(NC * 256);
    float* lp1  = alloc(NC);
    float* lp2  = alloc(NC);
    // bf16 weight planes: [3][1024][Ksp]
    ushort* WqP  = allocU((size_t)3 * 1024 * 320);
    ushort* WpP  = allocU((size_t)3 * 1024 * 320);
    ushort* Wm1P = allocU((size_t)3 * 1024 * 1024);
    ushort* Wm2P = allocU((size_t)3 * 1024 * 256);
    ushort* WoP  = allocU((size_t)3 * 1024 * 256);
    (void)ws_size; (void)in_sizes; (void)n_in; (void)out_size;

    // ---- weight splits ----
    splitW_k<<<dim3(1024 * 80 / 256), 256, 0, stream>>>(qenc_Wih, WqP, 300, 320);
    splitW_k<<<dim3(1024 * 80 / 256), 256, 0, stream>>>(penc_Wih, WpP, 300, 320);
    splitW_k<<<dim3(1024 * 256 / 256), 256, 0, stream>>>(m1_Wih, Wm1P, 1024, 1024);
    splitW_k<<<dim3(1024 * 64 / 256), 256, 0, stream>>>(m2_Wih, Wm2P, 256, 256);
    splitW_k<<<dim3(1024 * 64 / 256), 256, 0, stream>>>(out_Wih, WoP, 256, 256);

    // ---- encoders (scans fused across P/Q: 256 blocks) ----
    gemm_bf16x3<<<dim3((int)(NQ / TM), 4, 2), 256, 0, stream>>>(emb, q, WqP, qenc_b, xgQ, (int)NQ, 300, 320);
    gemm_bf16x3<<<dim3((int)(NC / TM), 4, 2), 256, 0, stream>>>(emb, p, WpP, penc_b, xgA, (int)NC, 300, 320);
    lstm_scan3<<<dim3(BB, 2, 2), 512, 0, stream>>>(xgA, penc_Whh, co, CL,
                                                   xgQ, qenc_Whh, qo, QL);

    // ---- attention ----
    rowdot<<<dim3((int)(NC * 64 / 256)), 256, 0, stream>>>(co, att_wc, cw, (int)NC, 256);
    rowdot<<<dim3((int)(NQ * 64 / 256)), 256, 0, stream>>>(qo, att_wq, qw, (int)NQ, 256);
    att_s<<<dim3(BB, CL / 64), 256, 0, stream>>>(co, qo, cw, qw, att_wcq, att_b, sbuf);
    softmax_q<<<dim3((int)(NC * 64 / 256)), 256, 0, stream>>>(sbuf, smax);
    bw_k<<<dim3(BB), 512, 0, stream>>>(smax, bw);
    q2c_k<<<dim3(BB), 256, 0, stream>>>(bw, co, q2c);
    c2q_g<<<dim3(BB, CL / 64), 256, 0, stream>>>(sbuf, qo, co, q2c, gbuf);

    // ---- modeling layers ----
    gemm_bf16x3<<<dim3((int)(NC / TM), 4, 2), 256, 0, stream>>>(gbuf, nullptr, Wm1P, m1_b, xgA, (int)NC, 1024, 1024);
    lstm_scan3<<<dim3(BB, 2, 1), 512, 0, stream>>>(xgA, m1_Whh, mmid, CL,
                                                   xgA, m1_Whh, mmid, CL);
    gemm_bf16x3<<<dim3((int)(NC / TM), 4, 2), 256, 0, stream>>>(mmid, nullptr, Wm2P, m2_b, xgA, (int)NC, 256, 256);
    lstm_scan3<<<dim3(BB, 2, 1), 512, 0, stream>>>(xgA, m2_Whh, mbuf, CL,
                                                   xgA, m2_Whh, mbuf, CL);
    gemm_bf16x3<<<dim3((int)(NC / TM), 4, 2), 256, 0, stream>>>(mbuf, nullptr, WoP, out_b, xgA, (int)NC, 256, 256);
    lstm_scan3<<<dim3(BB, 2, 1), 512, 0, stream>>>(xgA, out_Whh, m2o, CL,
                                                   xgA, out_Whh, m2o, CL);

    // ---- output ----
    logits_k<<<dim3((int)(NC * 64 / 256)), 256, 0, stream>>>(gbuf, mbuf, m2o,
        p1_wg, p1_wm, p1_b, p2_wg, p2_wm, p2_b, lp1, lp2);
    masked_softmax<<<dim3(BB, 2), 512, 0, stream>>>(lp1, lp2, p, (float*)d_out);
}